// Round 1
// baseline (181.592 us; speedup 1.0000x reference)
//
#include <hip/hip_runtime.h>
#include <math.h>

// Problem constants (fixed by the reference's setup_inputs)
#define NN   262144
#define MM   2048
#define LCH  64              // steps per chunk
#define CCH  (NN / LCH)      // 4096 chunks
#define CPT  (CCH / 256)     // 16 chunks per thread in the scan kernel
#define GRAV 9.81007f

struct Qt { float x, y, z, w; };
struct V3 { float x, y, z; };

__device__ __forceinline__ V3 v3(float x, float y, float z) { V3 r{x, y, z}; return r; }
__device__ __forceinline__ V3 vadd(V3 a, V3 b) { return v3(a.x + b.x, a.y + b.y, a.z + b.z); }
__device__ __forceinline__ V3 vscale(V3 a, float s) { return v3(a.x * s, a.y * s, a.z * s); }
__device__ __forceinline__ float vdot(V3 a, V3 b) { return a.x * b.x + a.y * b.y + a.z * b.z; }

__device__ __forceinline__ Qt qmul(Qt a, Qt b) {
    Qt r;
    r.x = a.w * b.x + a.x * b.w + a.y * b.z - a.z * b.y;
    r.y = a.w * b.y - a.x * b.z + a.y * b.w + a.z * b.x;
    r.z = a.w * b.z + a.x * b.y - a.y * b.x + a.z * b.w;
    r.w = a.w * b.w - a.x * b.x - a.y * b.y - a.z * b.z;
    return r;
}
__device__ __forceinline__ Qt qnorm(Qt a) {
    float rn = rsqrtf(a.x * a.x + a.y * a.y + a.z * a.z + a.w * a.w);
    Qt r{a.x * rn, a.y * rn, a.z * rn, a.w * rn};
    return r;
}
__device__ __forceinline__ V3 qrot(Qt q, V3 v) {
    float tx = 2.f * (q.y * v.z - q.z * v.y);
    float ty = 2.f * (q.z * v.x - q.x * v.z);
    float tz = 2.f * (q.x * v.y - q.y * v.x);
    V3 r;
    r.x = v.x + q.w * tx + (q.y * tz - q.z * ty);
    r.y = v.y + q.w * ty + (q.z * tx - q.x * tz);
    r.z = v.z + q.w * tz + (q.x * ty - q.y * tx);
    return r;
}
__device__ __forceinline__ Qt exp_so3(V3 phi) {
    float t2 = vdot(phi, phi);
    float th = sqrtf(t2);
    float h = 0.5f * th;
    float s, c;
    if (h < 0.1f) {  // |gyro|*dt ~ 5e-4 rad -> this branch is taken uniformly
        float h2 = h * h;
        s = 0.5f * (1.f - h2 * (1.f / 6.f) + h2 * h2 * (1.f / 120.f));
        c = 1.f - h2 * 0.5f + h2 * h2 * (1.f / 24.f);
    } else {
        s = 0.5f * sinf(h) / h;
        c = cosf(h);
    }
    Qt r{phi.x * s, phi.y * s, phi.z * s, c};
    return r;
}

__device__ __forceinline__ void step_state(Qt& q, V3& v, V3& p, V3 a, V3 w, float dt) {
    V3 aw = qrot(q, a);
    aw.z -= GRAV;
    float hdt2 = 0.5f * dt * dt;
    p.x += v.x * dt + aw.x * hdt2;
    p.y += v.y * dt + aw.y * hdt2;
    p.z += v.z * dt + aw.z * hdt2;
    v.x += aw.x * dt;
    v.y += aw.y * dt;
    v.z += aw.z * dt;
    q = qnorm(qmul(q, exp_so3(v3(w.x * dt, w.y * dt, w.z * dt))));
}

// Chunk summary: affine map on (q,v,p).
//   q' = q*Q ;  v' = v + qrot(q,B1) + g*T ;  p' = p + v*T + qrot(q,C) + g*W
struct Sm { Qt q; float T; V3 B1; V3 C; float W; };

__device__ __forceinline__ Sm sm_combine(const Sm& a, const Sm& b) {
    Sm r;
    r.q  = qnorm(qmul(a.q, b.q));
    r.T  = a.T + b.T;
    r.B1 = vadd(a.B1, qrot(a.q, b.B1));
    r.C  = vadd(vadd(a.C, vscale(a.B1, b.T)), qrot(a.q, b.C));
    r.W  = a.W + a.T * b.T + b.W;
    return r;
}
__device__ __forceinline__ void sm_store(float* p, const Sm& s) {
    p[0] = s.q.x; p[1] = s.q.y; p[2] = s.q.z; p[3] = s.q.w;
    p[4] = s.T;
    p[5] = s.B1.x; p[6] = s.B1.y; p[7] = s.B1.z;
    p[8] = s.C.x;  p[9] = s.C.y;  p[10] = s.C.z;
    p[11] = s.W;
}
__device__ __forceinline__ Sm sm_load(const float* p) {
    Sm s;
    s.q = Qt{p[0], p[1], p[2], p[3]};
    s.T = p[4];
    s.B1 = v3(p[5], p[6], p[7]);
    s.C  = v3(p[8], p[9], p[10]);
    s.W = p[11];
    return s;
}

// Apply prefix summary P to initial state and write carry record (10 floats used).
__device__ __forceinline__ void apply_write(const Sm& P, Qt q0, V3 v0, V3 p0, float* o) {
    Qt qc = qnorm(qmul(q0, P.q));
    V3 vb = qrot(q0, P.B1);
    V3 pb = qrot(q0, P.C);
    o[0] = qc.x; o[1] = qc.y; o[2] = qc.z; o[3] = qc.w;
    o[4] = v0.x + vb.x;
    o[5] = v0.y + vb.y;
    o[6] = v0.z + vb.z - GRAV * P.T;
    o[7] = p0.x + v0.x * P.T + pb.x;
    o[8] = p0.y + v0.y * P.T + pb.y;
    o[9] = p0.z + v0.z * P.T + pb.z - GRAV * P.W;
}

// ---------------- Kernel 1: per-chunk summaries (4096 threads) ----------------
__global__ __launch_bounds__(256) void k_chunk(
    const float* __restrict__ acc, const float* __restrict__ gyr,
    const float* __restrict__ ab, const float* __restrict__ gb,
    const float* __restrict__ dts, float* __restrict__ sums) {
    int c = blockIdx.x * blockDim.x + threadIdx.x;
    if (c >= CCH) return;
    float ab0 = ab[0], ab1 = ab[1], ab2 = ab[2];
    float gb0 = gb[0], gb1 = gb[1], gb2 = gb[2];
    Qt q{0.f, 0.f, 0.f, 1.f};
    V3 B1 = v3(0, 0, 0), B2 = v3(0, 0, 0);
    float t = 0.f, U = 0.f;
    const float* ap = acc + (size_t)c * LCH * 3;
    const float* gp = gyr + (size_t)c * LCH * 3;
    const float* dp = dts + (size_t)c * LCH;
    for (int j = 0; j < LCH; ++j) {
        V3 a = v3(ap[3 * j] - ab0, ap[3 * j + 1] - ab1, ap[3 * j + 2] - ab2);
        V3 w = v3(gp[3 * j] - gb0, gp[3 * j + 1] - gb1, gp[3 * j + 2] - gb2);
        float dt = dp[j];
        V3 b = qrot(q, a);          // local-frame rotated accel (q at interval start)
        float tc = t + 0.5f * dt;
        B1 = vadd(B1, vscale(b, dt));
        B2 = vadd(B2, vscale(b, dt * tc));
        U += dt * tc;
        t += dt;
        q = qnorm(qmul(q, exp_so3(v3(w.x * dt, w.y * dt, w.z * dt))));
    }
    Sm s;
    s.q = q; s.T = t; s.B1 = B1;
    s.C = vadd(vscale(B1, t), vscale(B2, -1.f));  // T*B1 - B2
    s.W = t * t - U;
    sm_store(sums + (size_t)c * 12, s);
}

// ---------------- Kernel 2: scan over 4096 summaries -> 4097 carries ----------------
__global__ __launch_bounds__(256) void k_scan(
    const float* __restrict__ sums,
    const float* __restrict__ q0p, const float* __restrict__ p0p, const float* __restrict__ v0p,
    float* __restrict__ carry, float* __restrict__ accum) {
    __shared__ float ls[256][12];
    int tid = threadIdx.x;
    // sequential combine of own 16 chunks
    Sm tot = sm_load(sums + (size_t)tid * CPT * 12);
    for (int k = 1; k < CPT; ++k)
        tot = sm_combine(tot, sm_load(sums + (size_t)(tid * CPT + k) * 12));
    sm_store(ls[tid], tot);
    // Hillis-Steele inclusive scan over 256 thread-totals
    for (int off = 1; off < 256; off <<= 1) {
        __syncthreads();
        Sm t = sm_load(ls[tid]);
        if (tid >= off) t = sm_combine(sm_load(ls[tid - off]), t);
        __syncthreads();
        sm_store(ls[tid], t);
    }
    __syncthreads();
    Sm P;
    if (tid == 0) { P.q = Qt{0, 0, 0, 1}; P.T = 0; P.B1 = v3(0, 0, 0); P.C = v3(0, 0, 0); P.W = 0; }
    else P = sm_load(ls[tid - 1]);
    Qt q0{q0p[0], q0p[1], q0p[2], q0p[3]};
    V3 p0 = v3(p0p[0], p0p[1], p0p[2]);
    V3 v0 = v3(v0p[0], v0p[1], v0p[2]);
    for (int k = 0; k < CPT; ++k) {
        int ch = tid * CPT + k;
        apply_write(P, q0, v0, p0, carry + (size_t)ch * 12);
        P = sm_combine(P, sm_load(sums + (size_t)ch * 12));
    }
    if (tid == 255) apply_write(P, q0, v0, p0, carry + (size_t)CCH * 12);  // end state
    if (tid == 0) { accum[0] = 0.f; accum[1] = 0.f; }
}

// ---------------- Kernel 3: sync-point evaluation + reduction (2048 threads) ----------------
__global__ __launch_bounds__(256) void k_sync(
    const float* __restrict__ acc, const float* __restrict__ gyr,
    const float* __restrict__ ab, const float* __restrict__ gb,
    const float* __restrict__ dts, const float* __restrict__ carry,
    const float* __restrict__ prot, const float* __restrict__ ptrn,
    const int* __restrict__ sync, float* __restrict__ accum) {
    int m = blockIdx.x * blockDim.x + threadIdx.x;
    float rsq = 0.f, tsq = 0.f;
    if (m < MM) {
        int g = sync[m] + 1;       // state AFTER step sync[m]
        int c = g >> 6;            // LCH = 64
        int r = g & (LCH - 1);
        const float* cy = carry + (size_t)c * 12;
        Qt q{cy[0], cy[1], cy[2], cy[3]};
        V3 v = v3(cy[4], cy[5], cy[6]);
        V3 p = v3(cy[7], cy[8], cy[9]);
        float ab0 = ab[0], ab1 = ab[1], ab2 = ab[2];
        float gb0 = gb[0], gb1 = gb[1], gb2 = gb[2];
        int base = c * LCH;
        for (int j = 0; j < r; ++j) {
            int i = base + j;
            V3 a = v3(acc[3 * i] - ab0, acc[3 * i + 1] - ab1, acc[3 * i + 2] - ab2);
            V3 w = v3(gyr[3 * i] - gb0, gyr[3 * i + 1] - gb1, gyr[3 * i + 2] - gb2);
            step_state(q, v, p, a, w, dts[i]);
        }
        Qt pr{prot[4 * m], prot[4 * m + 1], prot[4 * m + 2], prot[4 * m + 3]};
        Qt pc{-pr.x, -pr.y, -pr.z, pr.w};
        Qt rel = qmul(pc, q);
        float nn = sqrtf(rel.x * rel.x + rel.y * rel.y + rel.z * rel.z);
        float theta = 2.f * atan2f(nn, rel.w);
        float scale = (nn < 1e-7f) ? 2.f : theta / fmaxf(nn, 1e-12f);
        float lx = rel.x * scale, ly = rel.y * scale, lz = rel.z * scale;
        rsq = lx * lx + ly * ly + lz * lz;
        float dx = ptrn[3 * m] - p.x, dy = ptrn[3 * m + 1] - p.y, dz = ptrn[3 * m + 2] - p.z;
        tsq = dx * dx + dy * dy + dz * dz;
    }
    // wave-level reduce, one atomic per wave per accumulator
    for (int o = 32; o > 0; o >>= 1) {
        rsq += __shfl_down(rsq, o);
        tsq += __shfl_down(tsq, o);
    }
    if ((threadIdx.x & 63) == 0) {
        atomicAdd(&accum[0], rsq);
        atomicAdd(&accum[1], tsq);
    }
}

// ---------------- Kernel 4: finalize scalar ----------------
__global__ void k_fin(const float* __restrict__ accum, float* __restrict__ out) {
    out[0] = sqrtf(accum[0]) + accum[1] * (1.f / (3.f * MM));
}

extern "C" void kernel_launch(void* const* d_in, const int* in_sizes, int n_in,
                              void* d_out, int out_size, void* d_ws, size_t ws_size,
                              hipStream_t stream) {
    const float* acc  = (const float*)d_in[0];
    const float* gyr  = (const float*)d_in[1];
    const float* ab   = (const float*)d_in[2];
    const float* gb   = (const float*)d_in[3];
    const float* dts  = (const float*)d_in[4];
    const float* q0   = (const float*)d_in[5];
    const float* p0   = (const float*)d_in[6];   // init_pos comes before init_vel
    const float* v0   = (const float*)d_in[7];
    const float* prot = (const float*)d_in[8];
    const float* ptrn = (const float*)d_in[9];
    const int*   sync = (const int*)d_in[10];

    float* ws    = (float*)d_ws;
    float* sums  = ws;                                  // CCH*12 floats
    float* carry = ws + (size_t)CCH * 12;               // (CCH+1)*12 floats
    float* accum = carry + (size_t)(CCH + 1) * 12;      // 2 floats
    float* out   = (float*)d_out;

    hipLaunchKernelGGL(k_chunk, dim3(CCH / 256), dim3(256), 0, stream,
                       acc, gyr, ab, gb, dts, sums);
    hipLaunchKernelGGL(k_scan, dim3(1), dim3(256), 0, stream,
                       sums, q0, p0, v0, carry, accum);
    hipLaunchKernelGGL(k_sync, dim3(MM / 256), dim3(256), 0, stream,
                       acc, gyr, ab, gb, dts, carry, prot, ptrn, sync, accum);
    hipLaunchKernelGGL(k_fin, dim3(1), dim3(1), 0, stream, accum, out);
}

// Round 2
// 104.364 us; speedup vs baseline: 1.7400x; 1.7400x over previous
//
#include <hip/hip_runtime.h>
#include <math.h>

// Problem constants (fixed by the reference's setup_inputs)
#define NN   262144
#define MM   2048
#define SUB  16               // steps per thread
#define BT   64               // threads per block in k1 (1 wave)
#define SPB  (BT * SUB)       // 1024 steps per block
#define NB1  (NN / SPB)       // 256 blocks in k1
#define NTH  (NN / SUB)       // 16384 level-0 threads
#define REC  113              // per-thread LDS record stride (floats): 48+48+16 padded, odd -> conflict-free
#define GRAV 9.81007f

struct Qt { float x, y, z, w; };
struct V3 { float x, y, z; };

__device__ __forceinline__ V3 v3(float x, float y, float z) { V3 r{x, y, z}; return r; }
__device__ __forceinline__ V3 vadd(V3 a, V3 b) { return v3(a.x + b.x, a.y + b.y, a.z + b.z); }
__device__ __forceinline__ V3 vscale(V3 a, float s) { return v3(a.x * s, a.y * s, a.z * s); }
__device__ __forceinline__ float vdot(V3 a, V3 b) { return a.x * b.x + a.y * b.y + a.z * b.z; }

__device__ __forceinline__ Qt qmul(Qt a, Qt b) {
    Qt r;
    r.x = a.w * b.x + a.x * b.w + a.y * b.z - a.z * b.y;
    r.y = a.w * b.y - a.x * b.z + a.y * b.w + a.z * b.x;
    r.z = a.w * b.z + a.x * b.y - a.y * b.x + a.z * b.w;
    r.w = a.w * b.w - a.x * b.x - a.y * b.y - a.z * b.z;
    return r;
}
__device__ __forceinline__ Qt qnorm(Qt a) {
    float rn = rsqrtf(a.x * a.x + a.y * a.y + a.z * a.z + a.w * a.w);
    Qt r{a.x * rn, a.y * rn, a.z * rn, a.w * rn};
    return r;
}
__device__ __forceinline__ V3 qrot(Qt q, V3 v) {
    float tx = 2.f * (q.y * v.z - q.z * v.y);
    float ty = 2.f * (q.z * v.x - q.x * v.z);
    float tz = 2.f * (q.x * v.y - q.y * v.x);
    V3 r;
    r.x = v.x + q.w * tx + (q.y * tz - q.z * ty);
    r.y = v.y + q.w * ty + (q.z * tx - q.x * tz);
    r.z = v.z + q.w * tz + (q.x * ty - q.y * tx);
    return r;
}
__device__ __forceinline__ Qt exp_so3(V3 phi) {
    float t2 = vdot(phi, phi);
    float th = sqrtf(t2);
    float h = 0.5f * th;
    float s, c;
    if (h < 0.1f) {  // |gyro|*dt ~ 5e-4 rad -> uniformly taken
        float h2 = h * h;
        s = 0.5f * (1.f - h2 * (1.f / 6.f) + h2 * h2 * (1.f / 120.f));
        c = 1.f - h2 * 0.5f + h2 * h2 * (1.f / 24.f);
    } else {
        s = 0.5f * sinf(h) / h;
        c = cosf(h);
    }
    Qt r{phi.x * s, phi.y * s, phi.z * s, c};
    return r;
}

__device__ __forceinline__ void step_state(Qt& q, V3& v, V3& p, V3 a, V3 w, float dt) {
    V3 aw = qrot(q, a);
    aw.z -= GRAV;
    float hdt2 = 0.5f * dt * dt;
    p.x += v.x * dt + aw.x * hdt2;
    p.y += v.y * dt + aw.y * hdt2;
    p.z += v.z * dt + aw.z * hdt2;
    v.x += aw.x * dt;
    v.y += aw.y * dt;
    v.z += aw.z * dt;
    q = qnorm(qmul(q, exp_so3(v3(w.x * dt, w.y * dt, w.z * dt))));
}

// Chunk summary: affine map on (q,v,p).
//   q' = q*Q ;  v' = v + qrot(q,B1) + g*T ;  p' = p + v*T + qrot(q,C) + g*W
struct Sm { Qt q; float T; V3 B1; V3 C; float W; };

__device__ __forceinline__ Sm sm_identity() {
    Sm s; s.q = Qt{0, 0, 0, 1}; s.T = 0; s.B1 = v3(0, 0, 0); s.C = v3(0, 0, 0); s.W = 0; return s;
}
__device__ __forceinline__ Sm sm_combine(const Sm& a, const Sm& b) {
    Sm r;
    r.q  = qnorm(qmul(a.q, b.q));
    r.T  = a.T + b.T;
    r.B1 = vadd(a.B1, qrot(a.q, b.B1));
    r.C  = vadd(vadd(a.C, vscale(a.B1, b.T)), qrot(a.q, b.C));
    r.W  = a.W + a.T * b.T + b.W;
    return r;
}
__device__ __forceinline__ void sm_store(float* p, const Sm& s) {
    p[0] = s.q.x; p[1] = s.q.y; p[2] = s.q.z; p[3] = s.q.w;
    p[4] = s.T;
    p[5] = s.B1.x; p[6] = s.B1.y; p[7] = s.B1.z;
    p[8] = s.C.x;  p[9] = s.C.y;  p[10] = s.C.z;
    p[11] = s.W;
}
__device__ __forceinline__ Sm sm_load(const float* p) {
    Sm s;
    s.q = Qt{p[0], p[1], p[2], p[3]};
    s.T = p[4];
    s.B1 = v3(p[5], p[6], p[7]);
    s.C  = v3(p[8], p[9], p[10]);
    s.W = p[11];
    return s;
}
__device__ __forceinline__ Sm sm_shfl_up(const Sm& s, int off) {
    Sm r;
    r.q.x = __shfl_up(s.q.x, off); r.q.y = __shfl_up(s.q.y, off);
    r.q.z = __shfl_up(s.q.z, off); r.q.w = __shfl_up(s.q.w, off);
    r.T = __shfl_up(s.T, off);
    r.B1.x = __shfl_up(s.B1.x, off); r.B1.y = __shfl_up(s.B1.y, off); r.B1.z = __shfl_up(s.B1.z, off);
    r.C.x = __shfl_up(s.C.x, off);  r.C.y = __shfl_up(s.C.y, off);  r.C.z = __shfl_up(s.C.z, off);
    r.W = __shfl_up(s.W, off);
    return r;
}

// State record (q,v,p) -- stored with stride 12 floats (10 used)
struct St { Qt q; V3 v; V3 p; };
__device__ __forceinline__ St apply_sm(const Sm& P, Qt q0, V3 v0, V3 p0) {
    St s;
    s.q = qnorm(qmul(q0, P.q));
    V3 vb = qrot(q0, P.B1);
    V3 pb = qrot(q0, P.C);
    s.v = v3(v0.x + vb.x, v0.y + vb.y, v0.z + vb.z - GRAV * P.T);
    s.p = v3(p0.x + v0.x * P.T + pb.x,
             p0.y + v0.y * P.T + pb.y,
             p0.z + v0.z * P.T + pb.z - GRAV * P.W);
    return s;
}
__device__ __forceinline__ void st_store(float* p, const St& s) {
    p[0] = s.q.x; p[1] = s.q.y; p[2] = s.q.z; p[3] = s.q.w;
    p[4] = s.v.x; p[5] = s.v.y; p[6] = s.v.z;
    p[7] = s.p.x; p[8] = s.p.y; p[9] = s.p.z;
}
__device__ __forceinline__ St st_load(const float* p) {
    St s;
    s.q = Qt{p[0], p[1], p[2], p[3]};
    s.v = v3(p[4], p[5], p[6]);
    s.p = v3(p[7], p[8], p[9]);
    return s;
}

// ------- Kernel 1: per-thread 16-step summaries + intra-wave inclusive scan -------
// 256 blocks x 64 threads (1 wave/block, one block per CU).
__global__ __launch_bounds__(BT) void k_sum(
    const float* __restrict__ acc, const float* __restrict__ gyr,
    const float* __restrict__ ab, const float* __restrict__ gb,
    const float* __restrict__ dts,
    float* __restrict__ prefix, float* __restrict__ blocksums) {
    __shared__ float lds[BT * REC];   // per-thread record: acc[48] gyr[48] dts[16] pad[1]
    int b = blockIdx.x;
    int t = threadIdx.x;

    // ---- coalesced staging: acc (3072 floats = 768 float4) ----
    const float4* ga = (const float4*)(acc + (size_t)b * SPB * 3);
    const float4* gg = (const float4*)(gyr + (size_t)b * SPB * 3);
    const float4* gd = (const float4*)(dts + (size_t)b * SPB);
#pragma unroll
    for (int r = 0; r < 12; ++r) {
        int i4 = r * BT + t;
        float4 v = ga[i4];
        int i = i4 * 4;
        float* d = &lds[(i / 48) * REC + (i % 48)];
        d[0] = v.x; d[1] = v.y; d[2] = v.z; d[3] = v.w;
    }
#pragma unroll
    for (int r = 0; r < 12; ++r) {
        int i4 = r * BT + t;
        float4 v = gg[i4];
        int i = i4 * 4;
        float* d = &lds[(i / 48) * REC + 48 + (i % 48)];
        d[0] = v.x; d[1] = v.y; d[2] = v.z; d[3] = v.w;
    }
#pragma unroll
    for (int r = 0; r < 4; ++r) {
        int i4 = r * BT + t;
        float4 v = gd[i4];
        int i = i4 * 4;
        float* d = &lds[(i / 16) * REC + 96 + (i % 16)];
        d[0] = v.x; d[1] = v.y; d[2] = v.z; d[3] = v.w;
    }
    __syncthreads();

    float ab0 = ab[0], ab1 = ab[1], ab2 = ab[2];
    float gb0 = gb[0], gb1 = gb[1], gb2 = gb[2];

    // ---- 16-step local summary ----
    const float* rec = &lds[t * REC];
    Qt q{0.f, 0.f, 0.f, 1.f};
    V3 B1 = v3(0, 0, 0), B2 = v3(0, 0, 0);
    float tt = 0.f, U = 0.f;
#pragma unroll
    for (int j = 0; j < SUB; ++j) {
        V3 a = v3(rec[3 * j] - ab0, rec[3 * j + 1] - ab1, rec[3 * j + 2] - ab2);
        V3 w = v3(rec[48 + 3 * j] - gb0, rec[48 + 3 * j + 1] - gb1, rec[48 + 3 * j + 2] - gb2);
        float dt = rec[96 + j];
        V3 bb = qrot(q, a);
        float tc = tt + 0.5f * dt;
        B1 = vadd(B1, vscale(bb, dt));
        B2 = vadd(B2, vscale(bb, dt * tc));
        U += dt * tc;
        tt += dt;
        q = qnorm(qmul(q, exp_so3(v3(w.x * dt, w.y * dt, w.z * dt))));
    }
    Sm cur;
    cur.q = q; cur.T = tt; cur.B1 = B1;
    cur.C = vadd(vscale(B1, tt), vscale(B2, -1.f));   // T*B1 - B2
    cur.W = tt * tt - U;

    // ---- intra-wave inclusive scan (non-commutative: older-left) ----
#pragma unroll
    for (int off = 1; off < 64; off <<= 1) {
        Sm o = sm_shfl_up(cur, off);
        if (t >= off) cur = sm_combine(o, cur);
    }
    sm_store(prefix + (size_t)(b * BT + t) * 12, cur);
    if (t == BT - 1) sm_store(blocksums + (size_t)b * 12, cur);
}

// ------- Kernel 2: scan 256 block totals -> 257 block-boundary states -------
__global__ __launch_bounds__(NB1) void k_scan(
    const float* __restrict__ blocksums,
    const float* __restrict__ q0p, const float* __restrict__ p0p, const float* __restrict__ v0p,
    float* __restrict__ S, float* __restrict__ accum) {
    __shared__ float ls[NB1][12];
    int tid = threadIdx.x;
    Sm cur = sm_load(blocksums + (size_t)tid * 12);
    sm_store(ls[tid], cur);
    for (int off = 1; off < NB1; off <<= 1) {
        __syncthreads();
        Sm t = sm_load(ls[tid]);
        if (tid >= off) t = sm_combine(sm_load(ls[tid - off]), t);
        __syncthreads();
        sm_store(ls[tid], t);
    }
    __syncthreads();
    Qt q0{q0p[0], q0p[1], q0p[2], q0p[3]};
    V3 p0 = v3(p0p[0], p0p[1], p0p[2]);
    V3 v0 = v3(v0p[0], v0p[1], v0p[2]);
    Sm incl = sm_load(ls[tid]);
    St s = apply_sm(incl, q0, v0, p0);
    st_store(S + (size_t)(tid + 1) * 12, s);
    if (tid == 0) {
        St s0; s0.q = qnorm(q0); s0.v = v0; s0.p = p0;
        st_store(S, s0);
        accum[0] = 0.f; accum[1] = 0.f;
    }
}

// ------- Kernel 3: sync-point evaluation + reduction (32 blocks x 64) -------
__global__ __launch_bounds__(64) void k_sync(
    const float* __restrict__ acc, const float* __restrict__ gyr,
    const float* __restrict__ ab, const float* __restrict__ gb,
    const float* __restrict__ dts,
    const float* __restrict__ prefix, const float* __restrict__ S,
    const float* __restrict__ prot, const float* __restrict__ ptrn,
    const int* __restrict__ sync, float* __restrict__ accum) {
    int m = blockIdx.x * blockDim.x + threadIdx.x;
    float rsq = 0.f, tsq = 0.f;
    if (m < MM) {
        int g = sync[m] + 1;           // state AFTER step sync[m], in [1, NN]
        int b = g >> 10;               // SPB = 1024
        int t = (g >> 4) & (BT - 1);   // SUB = 16
        int r = g & (SUB - 1);
        St st = st_load(S + (size_t)b * 12);
        if (t > 0) {
            Sm P = sm_load(prefix + (size_t)(b * BT + t - 1) * 12);
            st = apply_sm(P, st.q, st.v, st.p);
        }
        if (r > 0) {
            float ab0 = ab[0], ab1 = ab[1], ab2 = ab[2];
            float gb0 = gb[0], gb1 = gb[1], gb2 = gb[2];
            int base = g & ~(SUB - 1);
            for (int j = 0; j < r; ++j) {
                int i = base + j;
                V3 a = v3(acc[3 * i] - ab0, acc[3 * i + 1] - ab1, acc[3 * i + 2] - ab2);
                V3 w = v3(gyr[3 * i] - gb0, gyr[3 * i + 1] - gb1, gyr[3 * i + 2] - gb2);
                step_state(st.q, st.v, st.p, a, w, dts[i]);
            }
        }
        Qt pr{prot[4 * m], prot[4 * m + 1], prot[4 * m + 2], prot[4 * m + 3]};
        Qt pc{-pr.x, -pr.y, -pr.z, pr.w};
        Qt rel = qmul(pc, st.q);
        float nn = sqrtf(rel.x * rel.x + rel.y * rel.y + rel.z * rel.z);
        float theta = 2.f * atan2f(nn, rel.w);
        float scale = (nn < 1e-7f) ? 2.f : theta / fmaxf(nn, 1e-12f);
        float lx = rel.x * scale, ly = rel.y * scale, lz = rel.z * scale;
        rsq = lx * lx + ly * ly + lz * lz;
        float dx = ptrn[3 * m] - st.p.x, dy = ptrn[3 * m + 1] - st.p.y, dz = ptrn[3 * m + 2] - st.p.z;
        tsq = dx * dx + dy * dy + dz * dz;
    }
    // wave-level reduce, one atomic per wave per accumulator
    for (int o = 32; o > 0; o >>= 1) {
        rsq += __shfl_down(rsq, o);
        tsq += __shfl_down(tsq, o);
    }
    if ((threadIdx.x & 63) == 0) {
        atomicAdd(&accum[0], rsq);
        atomicAdd(&accum[1], tsq);
    }
}

// ------- Kernel 4: finalize scalar -------
__global__ void k_fin(const float* __restrict__ accum, float* __restrict__ out) {
    out[0] = sqrtf(accum[0]) + accum[1] * (1.f / (3.f * MM));
}

extern "C" void kernel_launch(void* const* d_in, const int* in_sizes, int n_in,
                              void* d_out, int out_size, void* d_ws, size_t ws_size,
                              hipStream_t stream) {
    const float* acc  = (const float*)d_in[0];
    const float* gyr  = (const float*)d_in[1];
    const float* ab   = (const float*)d_in[2];
    const float* gb   = (const float*)d_in[3];
    const float* dts  = (const float*)d_in[4];
    const float* q0   = (const float*)d_in[5];
    const float* p0   = (const float*)d_in[6];   // init_pos precedes init_vel
    const float* v0   = (const float*)d_in[7];
    const float* prot = (const float*)d_in[8];
    const float* ptrn = (const float*)d_in[9];
    const int*   sync = (const int*)d_in[10];

    float* ws     = (float*)d_ws;
    float* prefix = ws;                                   // NTH*12 floats
    float* bsums  = prefix + (size_t)NTH * 12;            // NB1*12
    float* S      = bsums + (size_t)NB1 * 12;             // (NB1+1)*12
    float* accum  = S + (size_t)(NB1 + 1) * 12;           // 2
    float* out    = (float*)d_out;

    hipLaunchKernelGGL(k_sum, dim3(NB1), dim3(BT), 0, stream,
                       acc, gyr, ab, gb, dts, prefix, bsums);
    hipLaunchKernelGGL(k_scan, dim3(1), dim3(NB1), 0, stream,
                       bsums, q0, p0, v0, S, accum);
    hipLaunchKernelGGL(k_sync, dim3(MM / 64), dim3(64), 0, stream,
                       acc, gyr, ab, gb, dts, prefix, S, prot, ptrn, sync, accum);
    hipLaunchKernelGGL(k_fin, dim3(1), dim3(1), 0, stream, accum, out);
}